// Round 5
// baseline (130.994 us; speedup 1.0000x reference)
//
#include <hip/hip_runtime.h>
#include <math.h>

#define BB 64
#define RR 36
#define WW 50
#define DD 1024
#define EPSF 1e-8f

#define GM 2304   // 64*36
#define GN 3200   // 64*50
#define GK 1024
#define TSL ((size_t)GM * GN)   // one split-K slice of T

typedef __attribute__((ext_vector_type(8))) short bf16x8;
typedef __attribute__((ext_vector_type(4))) float f32x4;

#define GLL(src, dst) __builtin_amdgcn_global_load_lds( \
    (const __attribute__((address_space(1))) void*)(src), \
    (__attribute__((address_space(3))) void*)(dst), 16, 0, 0)

__device__ __forceinline__ unsigned short f2bf(float x) {
    unsigned int u = __float_as_uint(x);
    unsigned int r = (u + 0x7fffu + ((u >> 16) & 1u)) >> 16;   // RTN-even
    return (unsigned short)r;
}
__device__ __forceinline__ float bf2f(unsigned short h) {
    return __uint_as_float(((unsigned int)h) << 16);
}

// Redundant per-wave 64-wide scans over the 64-entry lens arrays (cheap; avoids
// an extra kernel + cross-block dependency for prefix sums).
__device__ __forceinline__ int wave_sum64(const int* __restrict__ a, int lane) {
    int v = a[lane];
    #pragma unroll
    for (int off = 32; off > 0; off >>= 1) v += __shfl_xor(v, off, 64);
    return v;
}
__device__ __forceinline__ int wave_excl_at(const int* __restrict__ a, int idx, int lane) {
    int v = a[lane], inc = v;
    #pragma unroll
    for (int off = 1; off < 64; off <<= 1) {
        int t = __shfl_up(inc, off, 64);
        if (lane >= off) inc += t;
    }
    return __shfl(inc - v, idx, 64);
}

// Phase 1: wave-per-row hi/lo split + row norm, writing VALID rows only, packed
// (validity compaction: ~51% of rows are valid on average). No barriers.
__global__ __launch_bounds__(256) void phase1_kernel(
        const float* __restrict__ imgs, const float* __restrict__ caps,
        const int* __restrict__ img_lens, const int* __restrict__ cap_lens,
        unsigned short* __restrict__ Ah, unsigned short* __restrict__ Al,
        unsigned short* __restrict__ Bh, unsigned short* __restrict__ Bl,
        float* __restrict__ invI, float* __restrict__ invC) {
    int tid = threadIdx.x;
    int lane = tid & 63, wv = tid >> 6;
    int row = blockIdx.x * 4 + wv;          // GM divisible by 4: no straddle
    const float* X;
    unsigned short *H, *L;
    float* invN;
    size_t srcr;
    int dst;
    if (row < GM) {
        int i = row / RR, r = row - i * RR;
        if (r >= img_lens[i]) return;        // wave-uniform exit; no barriers
        dst = wave_excl_at(img_lens, i, lane) + r;
        X = imgs; H = Ah; L = Al; invN = invI; srcr = (size_t)row;
    } else {
        int rc = row - GM;
        int c = rc / WW, w = rc - c * WW;
        if (w >= cap_lens[c]) return;
        dst = wave_excl_at(cap_lens, c, lane) + w;
        X = caps; H = Bh; L = Bl; invN = invC; srcr = (size_t)rc;
    }
    const float4* src = (const float4*)(X + srcr * DD);
    ushort4* Hd = (ushort4*)H + (size_t)dst * 256;
    ushort4* Ld = (ushort4*)L + (size_t)dst * 256;
    float ss = 0.f;
    #pragma unroll
    for (int j = 0; j < 4; j++) {
        float4 v = src[j * 64 + lane];
        float f[4] = {v.x, v.y, v.z, v.w};
        ushort4 hh, ll;
        unsigned short* hp = (unsigned short*)&hh;
        unsigned short* lp = (unsigned short*)&ll;
        #pragma unroll
        for (int jj = 0; jj < 4; jj++) {
            unsigned short hb = f2bf(f[jj]);
            hp[jj] = hb;
            lp[jj] = f2bf(f[jj] - bf2f(hb));
            ss = fmaf(f[jj], f[jj], ss);
        }
        Hd[j * 64 + lane] = hh;
        Ld[j * 64 + lane] = ll;
    }
    #pragma unroll
    for (int off = 32; off > 0; off >>= 1) ss += __shfl_down(ss, off, 64);
    if (lane == 0) invN[srcr] = 1.0f / (sqrtf(ss) + EPSF);   // original (i,r)/(c,w) index
}

// Phase 2: blocks [0,64) = gram (compacted B rows at prefC[c]); blocks
// [64, 64+3*450) = 128x128 GEMM over the COMPACTED M'xN' problem, SPLIT-K x3
// (k-steps 11/11/10 of 32): ~390 live GEMM blocks -> all 256 CUs busy at
// ~1.8 blocks/CU (the proven 33%-MfmaUtil regime) instead of 130 solo blocks.
// 2-buffer stage/compute, 1 barrier pair/step (round-1 proven structure).
__global__ __launch_bounds__(256) void phase2_kernel(
        const unsigned short* __restrict__ Ah, const unsigned short* __restrict__ Al,
        const unsigned short* __restrict__ Bh, const unsigned short* __restrict__ Bl,
        const int* __restrict__ img_lens, const int* __restrict__ cap_lens,
        unsigned short* __restrict__ Gh, float* __restrict__ T) {
    int bid = blockIdx.x, tid = threadIdx.x;
    int lane = tid & 63, wv = tid >> 6;
    int fm = lane & 15;
    __shared__ __align__(16) unsigned short lds[4][2][4096];   // 64 KiB

    int Nsz = wave_sum64(cap_lens, lane);

    if (bid < BB) {
        // ---- gram: G[c] = caps_c . caps_c^T (hi/lo 3-MFMA), K-chunks of 128.
        int c = bid;
        int pc = wave_excl_at(cap_lens, c, lane);
        unsigned short* H16 = &lds[0][0][0];   // 64 rows x 128 u (16 KiB)
        unsigned short* L16 = &lds[1][0][0];
        f32x4 acc[4] = {};
        for (int k0 = 0; k0 < GK; k0 += 128) {
            __syncthreads();                   // prev-iter reads done
            #pragma unroll
            for (int j = 0; j < 4; j++) {
                int R = (wv * 4 + j) * 4 + (lane >> 4);
                int rowR = pc + R;
                if (rowR > Nsz - 1) rowR = Nsz - 1;   // garbage killed in epi (m=0)
                int gg = (lane & 15) ^ (R & 7);       // XOR swizzle, 16B granules
                size_t srcoff = (size_t)rowR * GK + k0 + gg * 8;
                GLL(Bh + srcoff, &H16[(wv * 4 + j) * 512]);
                GLL(Bl + srcoff, &L16[(wv * 4 + j) * 512]);
            }
            __syncthreads();                   // drains vmcnt(0)
            #pragma unroll
            for (int ks = 0; ks < 4; ks++) {
                int Ra = wv * 16 + fm;
                int qa = ks * 4 + (lane >> 4);
                int oa = Ra * 128 + (qa ^ (Ra & 7)) * 8;
                bf16x8 ah = *(const bf16x8*)&H16[oa];
                bf16x8 al = *(const bf16x8*)&L16[oa];
                #pragma unroll
                for (int t = 0; t < 4; t++) {
                    int Rb = t * 16 + fm;
                    int ob = Rb * 128 + (qa ^ (Rb & 7)) * 8;
                    bf16x8 bh = *(const bf16x8*)&H16[ob];
                    bf16x8 bl = *(const bf16x8*)&L16[ob];
                    acc[t] = __builtin_amdgcn_mfma_f32_16x16x32_bf16(ah, bh, acc[t], 0, 0, 0);
                    acc[t] = __builtin_amdgcn_mfma_f32_16x16x32_bf16(ah, bl, acc[t], 0, 0, 0);
                    acc[t] = __builtin_amdgcn_mfma_f32_16x16x32_bf16(al, bh, acc[t], 0, 0, 0);
                }
            }
        }
        int row0 = wv * 16 + (lane >> 4) * 4;
        #pragma unroll
        for (int t = 0; t < 4; t++)
            #pragma unroll
            for (int v = 0; v < 4; v++)
                Gh[(size_t)c * 4096 + (row0 + v) * 64 + t * 16 + fm] = f2bf(acc[t][v]);
        return;
    }

    int q = bid - BB;
    int Msz = wave_sum64(img_lens, lane);
    int Mt = (Msz + 127) >> 7, Nt = (Nsz + 127) >> 7;
    int ntile = Mt * Nt;
    if (q >= 3 * ntile) return;               // dead block: uniform early exit
    int s = q / ntile;                        // k-slice 0..2
    int t = q - s * ntile;
    int m0 = (t / Nt) * 128, n0 = (t % Nt) * 128;
    int kbeg = s * 11, kcnt = (s == 2) ? 10 : 11;   // 32 k-steps split 11/11/10
    float* Ts = T + (size_t)s * TSL;

    int rw = (wv & 1) * 64;
    int cw = (wv >> 1) * 64;
    int srow = lane >> 2;
    // GLL dst is lane-ordered; XOR swizzle applied on the GLOBAL k-group
    int scol = ((lane & 3) ^ ((srow >> 1) & 3)) * 8;
    int fkS = ((lane >> 4) ^ ((fm >> 1) & 3)) * 8;

    f32x4 acc[4][4] = {};

    auto STAGE = [&](int buf, int kc) {
        int k0 = kc * 32;
        #pragma unroll
        for (int j = 0; j < 2; j++) {
            int seg = wv * 2 + j;
            int row = seg * 16 + srow;
            int rA = m0 + row; if (rA > Msz - 1) rA = Msz - 1;   // edge clamp
            int rB = n0 + row; if (rB > Nsz - 1) rB = Nsz - 1;   // (junk T unread)
            size_t ga = (size_t)rA * GK + k0 + scol;
            size_t gb = (size_t)rB * GK + k0 + scol;
            GLL(Ah + ga, &lds[0][buf][seg * 512]);
            GLL(Al + ga, &lds[1][buf][seg * 512]);
            GLL(Bh + gb, &lds[2][buf][seg * 512]);
            GLL(Bl + gb, &lds[3][buf][seg * 512]);
        }
    };
    auto COMPUTE = [&](int buf) {
        bf16x8 fah[4], fal[4], fbh[4], fbl[4];
        #pragma unroll
        for (int t2 = 0; t2 < 4; t2++) {
            int offa = (rw + t2 * 16 + fm) * 32 + fkS;
            int offb = (cw + t2 * 16 + fm) * 32 + fkS;
            fah[t2] = *(const bf16x8*)&lds[0][buf][offa];
            fal[t2] = *(const bf16x8*)&lds[1][buf][offa];
            fbh[t2] = *(const bf16x8*)&lds[2][buf][offb];
            fbl[t2] = *(const bf16x8*)&lds[3][buf][offb];
        }
        #pragma unroll
        for (int mt = 0; mt < 4; mt++)
            #pragma unroll
            for (int nt = 0; nt < 4; nt++) {
                acc[mt][nt] = __builtin_amdgcn_mfma_f32_16x16x32_bf16(
                    fah[mt], fbh[nt], acc[mt][nt], 0, 0, 0);
                acc[mt][nt] = __builtin_amdgcn_mfma_f32_16x16x32_bf16(
                    fah[mt], fbl[nt], acc[mt][nt], 0, 0, 0);
                acc[mt][nt] = __builtin_amdgcn_mfma_f32_16x16x32_bf16(
                    fal[mt], fbh[nt], acc[mt][nt], 0, 0, 0);
            }
    };

    // 2-phase pipeline: stage(k+1) issued before compute(k); single barrier
    // per k-step drains vmcnt(0) (next buffer ready) + orders LDS WAR.
    STAGE(0, kbeg);
    __syncthreads();
    int cur = 0;
    for (int kc = 1; kc < kcnt; ++kc) {
        STAGE(cur ^ 1, kbeg + kc);
        COMPUTE(cur);
        __syncthreads();
        cur ^= 1;
    }
    COMPUTE(cur);

    int orow0 = m0 + rw + (lane >> 4) * 4;
    int ocol0 = n0 + cw + fm;
    #pragma unroll
    for (int mt = 0; mt < 4; mt++)
        #pragma unroll
        for (int nt = 0; nt < 4; nt++)
            #pragma unroll
            for (int v = 0; v < 4; v++)
                Ts[(size_t)(orow0 + mt * 16 + v) * GN + ocol0 + nt * 16] = acc[mt][nt][v];
}

// Epilogue: one block per (c, i); T indexed via compaction prefixes and summed
// over the 3 split-K slices; row loop bounded by li.
#define MST 72   // sM row stride in ushorts (144 B, 16B-aligned)
__global__ __launch_bounds__(256) void epi_kernel(
        const float* __restrict__ T, const unsigned short* __restrict__ Gh,
        const int* __restrict__ img_lens, const int* __restrict__ cap_lens,
        const float* __restrict__ alpha,
        const float* __restrict__ invI, const float* __restrict__ invC,
        float* __restrict__ out) {
    int c = blockIdx.x, i = blockIdx.y;
    __shared__ __align__(16) unsigned short sGh[64 * 64];
    __shared__ __align__(16) unsigned short sMh[48 * MST];
    __shared__ __align__(16) float Hsh[36][68];
    __shared__ float numSh[36];
    __shared__ float part[36][4];

    int tid = threadIdx.x;
    int lane = tid & 63, wv = tid >> 6;
    int fm = lane & 15, fk8 = (lane >> 4) * 8;
    int hf = lane >> 5, l5 = lane & 31;

    int pI = wave_excl_at(img_lens, i, lane);
    int pC = wave_excl_at(cap_lens, c, lane);
    int lc = cap_lens[c], li = img_lens[i];

    {   // swizzled store: row r slot kg -> LDS slot kg ^ (r&7)
        const uint4* gh = (const uint4*)(Gh + (size_t)c * 4096);
        int rowg = tid >> 3, kg = tid & 7;
        int d = (rowg << 3) | (kg ^ (rowg & 7));
        ((uint4*)sGh)[d] = gh[tid];
        ((uint4*)sGh)[d + 256] = gh[tid + 256];
    }
    for (int t = tid; t < 12 * MST; t += 256) sMh[36 * MST + t] = 0;
    __syncthreads();

    bf16x8 gfh[2];
    #pragma unroll
    for (int ks = 0; ks < 2; ks++) {
        int kg8 = ks * 4 + (lane >> 4);
        int off = (wv * 16 + fm) * 64 + (kg8 ^ (fm & 7)) * 8;
        gfh[ks] = *(const bf16x8*)&sGh[off];
    }

    float a_mix = 1.0f / (1.0f + __expf(-alpha[0]));
    float oma = 1.0f - a_mix;
    float invC0 = invC[c * WW + l5];
    float invC1 = (l5 + 32 < WW) ? invC[c * WW + l5 + 32] : 0.f;
    bool v0 = l5 < lc, v1 = (l5 + 32) < lc;

    for (int r = wv * 2 + hf; r < li; r += 8) {
        float inv_ir = invI[i * RR + r];
        const float* Trow = T + (size_t)(pI + r) * GN + pC;
        float T0 = v0 ? (Trow[l5] + Trow[l5 + TSL] + Trow[l5 + 2 * TSL]) : 0.f;
        float T1 = v1 ? (Trow[l5 + 32] + Trow[l5 + 32 + TSL] + Trow[l5 + 32 + 2 * TSL]) : 0.f;
        float S0 = v0 ? (T0 * inv_ir * invC0) : -2.f;
        float S1 = v1 ? (T1 * inv_ir * invC1) : -2.f;
        float mv; int mi;
        if (S1 > S0) { mv = S1; mi = l5 + 32; } else { mv = S0; mi = l5; }
        #pragma unroll
        for (int m = 1; m < 32; m <<= 1) {
            float ov = __shfl_xor(mv, m, 32);
            int oi = __shfl_xor(mi, m, 32);
            if (ov > mv || (ov == mv && oi < mi)) { mv = ov; mi = oi; }
        }
        float e0 = v0 ? __expf((S0 - mv) * 10.f) : 0.f;
        float e1 = v1 ? __expf((S1 - mv) * 10.f) : 0.f;
        float ss = e0 + e1, nm = fmaf(e0, T0, e1 * T1);
        #pragma unroll
        for (int m = 1; m < 32; m <<= 1) {
            ss += __shfl_xor(ss, m, 32);
            nm += __shfl_xor(nm, m, 32);
        }
        float Tmi = (mi < 32) ? __shfl(T0, mi, 32) : __shfl(T1, mi - 32, 32);
        float scale = a_mix / ss;
        float m0 = e0 * scale + (l5 == mi ? oma : 0.f);
        float m1 = e1 * scale + (l5 + 32 == mi ? oma : 0.f);
        if (l5 == 0) numSh[r] = fmaf(nm, scale, oma * Tmi);
        sMh[r * MST + l5] = f2bf(m0);
        sMh[r * MST + l5 + 32] = f2bf(m1);
    }
    __syncthreads();

    int quad4 = (lane >> 4) * 4;
    #pragma unroll
    for (int mt = 0; mt < 3; mt++) {
        f32x4 acc = {0.f, 0.f, 0.f, 0.f};
        #pragma unroll
        for (int ks = 0; ks < 2; ks++) {
            int off = (mt * 16 + fm) * MST + ks * 32 + fk8;
            bf16x8 mh = *(const bf16x8*)&sMh[off];
            acc = __builtin_amdgcn_mfma_f32_16x16x32_bf16(mh, gfh[ks], acc, 0, 0, 0);
        }
        #pragma unroll
        for (int v = 0; v < 4; v++) {
            int row = mt * 16 + quad4 + v;
            if (row < RR) Hsh[row][wv * 16 + fm] = acc[v];
        }
    }
    __syncthreads();

    if (tid < 144) {
        int r = tid >> 2, j = tid & 3;
        const bf16x8* mh = (const bf16x8*)&sMh[r * MST + j * 16];
        float p = 0.f;
        #pragma unroll
        for (int g = 0; g < 2; g++) {
            bf16x8 h8 = mh[g];
            #pragma unroll
            for (int qq = 0; qq < 8; qq++) {
                float m = bf2f((unsigned short)h8[qq]);
                p = fmaf(m, Hsh[r][j * 16 + g * 8 + qq], p);
            }
        }
        part[r][j] = p;
    }
    __syncthreads();
    if (tid < RR) {
        float den2 = part[tid][0] + part[tid][1] + part[tid][2] + part[tid][3];
        float res = (tid < li) ? (numSh[tid] / (sqrtf(den2) + EPSF)) : -1.0f;
        out[((size_t)i * BB + c) * RR + tid] = res;
    }
}

extern "C" void kernel_launch(void* const* d_in, const int* in_sizes, int n_in,
                              void* d_out, int out_size, void* d_ws, size_t ws_size,
                              hipStream_t stream) {
    const float* imgs = (const float*)d_in[0];
    const float* caps = (const float*)d_in[1];
    const int* img_lens = (const int*)d_in[2];
    const int* cap_lens = (const int*)d_in[3];
    const float* alpha = (const float*)d_in[4];
    float* out = (float*)d_out;

    float* ws = (float*)d_ws;
    float* invI = ws;                              // 2304
    float* invC = ws + BB * RR;                    // 3200
    float* T = invC + BB * WW;                     // 3 x 7372800 (split-K slices)
    unsigned short* Ah = (unsigned short*)(T + 3 * TSL);
    unsigned short* Al = Ah + (size_t)GM * GK;
    unsigned short* Bh = Al + (size_t)GM * GK;
    unsigned short* Bl = Bh + (size_t)GN * GK;
    unsigned short* Gbh = Bl + (size_t)GN * GK;    // 64*4096 bf16

    phase1_kernel<<<(GM + GN) / 4, 256, 0, stream>>>(
        imgs, caps, img_lens, cap_lens, Ah, Al, Bh, Bl, invI, invC);
    phase2_kernel<<<BB + 3 * 450, 256, 0, stream>>>(
        Ah, Al, Bh, Bl, img_lens, cap_lens, Gbh, T);
    epi_kernel<<<dim3(BB, BB), 256, 0, stream>>>(
        T, Gbh, img_lens, cap_lens, alpha, invI, invC, out);
}

// Round 6
// 130.231 us; speedup vs baseline: 1.0059x; 1.0059x over previous
//
#include <hip/hip_runtime.h>
#include <math.h>

#define BB 64
#define RR 36
#define WW 50
#define DD 1024
#define EPSF 1e-8f

#define GM 2304   // 64*36
#define GN 3200   // 64*50
#define GK 1024

typedef __attribute__((ext_vector_type(8))) short bf16x8;
typedef __attribute__((ext_vector_type(4))) float f32x4;

#define GLL(src, dst) __builtin_amdgcn_global_load_lds( \
    (const __attribute__((address_space(1))) void*)(src), \
    (__attribute__((address_space(3))) void*)(dst), 16, 0, 0)

__device__ __forceinline__ unsigned short f2bf(float x) {
    unsigned int u = __float_as_uint(x);
    unsigned int r = (u + 0x7fffu + ((u >> 16) & 1u)) >> 16;   // RTN-even
    return (unsigned short)r;
}
__device__ __forceinline__ float bf2f(unsigned short h) {
    return __uint_as_float(((unsigned int)h) << 16);
}

// Redundant per-wave 64-wide scans over the 64-entry lens arrays (cheap; avoids
// an extra kernel + cross-block dependency for prefix sums).
__device__ __forceinline__ int wave_sum64(const int* __restrict__ a, int lane) {
    int v = a[lane];
    #pragma unroll
    for (int off = 32; off > 0; off >>= 1) v += __shfl_xor(v, off, 64);
    return v;
}
__device__ __forceinline__ int wave_excl_at(const int* __restrict__ a, int idx, int lane) {
    int v = a[lane], inc = v;
    #pragma unroll
    for (int off = 1; off < 64; off <<= 1) {
        int t = __shfl_up(inc, off, 64);
        if (lane >= off) inc += t;
    }
    return __shfl(inc - v, idx, 64);
}

// Phase 1: wave-per-row hi/lo split + row norm, writing VALID rows only, packed
// (validity compaction: ~51% of rows are valid on average). No barriers.
__global__ __launch_bounds__(256) void phase1_kernel(
        const float* __restrict__ imgs, const float* __restrict__ caps,
        const int* __restrict__ img_lens, const int* __restrict__ cap_lens,
        unsigned short* __restrict__ Ah, unsigned short* __restrict__ Al,
        unsigned short* __restrict__ Bh, unsigned short* __restrict__ Bl,
        float* __restrict__ invI, float* __restrict__ invC) {
    int tid = threadIdx.x;
    int lane = tid & 63, wv = tid >> 6;
    int row = blockIdx.x * 4 + wv;          // GM divisible by 4: no straddle
    const float* X;
    unsigned short *H, *L;
    float* invN;
    size_t srcr;
    int dst;
    if (row < GM) {
        int i = row / RR, r = row - i * RR;
        if (r >= img_lens[i]) return;        // wave-uniform exit; no barriers
        dst = wave_excl_at(img_lens, i, lane) + r;
        X = imgs; H = Ah; L = Al; invN = invI; srcr = (size_t)row;
    } else {
        int rc = row - GM;
        int c = rc / WW, w = rc - c * WW;
        if (w >= cap_lens[c]) return;
        dst = wave_excl_at(cap_lens, c, lane) + w;
        X = caps; H = Bh; L = Bl; invN = invC; srcr = (size_t)rc;
    }
    const float4* src = (const float4*)(X + srcr * DD);
    ushort4* Hd = (ushort4*)H + (size_t)dst * 256;
    ushort4* Ld = (ushort4*)L + (size_t)dst * 256;
    float ss = 0.f;
    #pragma unroll
    for (int j = 0; j < 4; j++) {
        float4 v = src[j * 64 + lane];
        float f[4] = {v.x, v.y, v.z, v.w};
        ushort4 hh, ll;
        unsigned short* hp = (unsigned short*)&hh;
        unsigned short* lp = (unsigned short*)&ll;
        #pragma unroll
        for (int jj = 0; jj < 4; jj++) {
            unsigned short hb = f2bf(f[jj]);
            hp[jj] = hb;
            lp[jj] = f2bf(f[jj] - bf2f(hb));
            ss = fmaf(f[jj], f[jj], ss);
        }
        Hd[j * 64 + lane] = hh;
        Ld[j * 64 + lane] = ll;
    }
    #pragma unroll
    for (int off = 32; off > 0; off >>= 1) ss += __shfl_down(ss, off, 64);
    if (lane == 0) invN[srcr] = 1.0f / (sqrtf(ss) + EPSF);   // original (i,r)/(c,w) index
}

// Phase 2: blocks [0,64) = gram (compacted B rows at prefC[c]); blocks
// [64, 64+450) = 128x128 GEMM over the COMPACTED M'xN'xK problem, depth-2
// prefetch (3 LDS buffers, counted vmcnt(8), raw s_barrier). Round-4 proven
// best configuration (no split-K: its extra T traffic cost more than the
// makespan it saved — round-5 measured regression).
__global__ __launch_bounds__(256) void phase2_kernel(
        const unsigned short* __restrict__ Ah, const unsigned short* __restrict__ Al,
        const unsigned short* __restrict__ Bh, const unsigned short* __restrict__ Bl,
        const int* __restrict__ img_lens, const int* __restrict__ cap_lens,
        unsigned short* __restrict__ Gh, float* __restrict__ T) {
    int bid = blockIdx.x, tid = threadIdx.x;
    int lane = tid & 63, wv = tid >> 6;
    int fm = lane & 15;
    __shared__ __align__(16) unsigned short lds[3][4][4096];   // 96 KiB

    int Nsz = wave_sum64(cap_lens, lane);

    if (bid < BB) {
        // ---- gram: G[c] = caps_c . caps_c^T (hi/lo 3-MFMA), K-chunks of 128.
        int c = bid;
        int pc = wave_excl_at(cap_lens, c, lane);
        unsigned short* H16 = &lds[0][0][0];   // 64 rows x 128 u (16 KiB)
        unsigned short* L16 = &lds[0][2][0];
        f32x4 acc[4] = {};
        for (int k0 = 0; k0 < GK; k0 += 128) {
            __syncthreads();                   // prev-iter reads done
            #pragma unroll
            for (int j = 0; j < 4; j++) {
                int R = (wv * 4 + j) * 4 + (lane >> 4);
                int rowR = pc + R;
                if (rowR > Nsz - 1) rowR = Nsz - 1;   // garbage killed in epi (m=0)
                int gg = (lane & 15) ^ (R & 7);       // XOR swizzle, 16B granules
                size_t srcoff = (size_t)rowR * GK + k0 + gg * 8;
                GLL(Bh + srcoff, &H16[(wv * 4 + j) * 512]);
                GLL(Bl + srcoff, &L16[(wv * 4 + j) * 512]);
            }
            __syncthreads();                   // drains vmcnt(0)
            #pragma unroll
            for (int ks = 0; ks < 4; ks++) {
                int Ra = wv * 16 + fm;
                int qa = ks * 4 + (lane >> 4);
                int oa = Ra * 128 + (qa ^ (Ra & 7)) * 8;
                bf16x8 ah = *(const bf16x8*)&H16[oa];
                bf16x8 al = *(const bf16x8*)&L16[oa];
                #pragma unroll
                for (int t = 0; t < 4; t++) {
                    int Rb = t * 16 + fm;
                    int ob = Rb * 128 + (qa ^ (Rb & 7)) * 8;
                    bf16x8 bh = *(const bf16x8*)&H16[ob];
                    bf16x8 bl = *(const bf16x8*)&L16[ob];
                    acc[t] = __builtin_amdgcn_mfma_f32_16x16x32_bf16(ah, bh, acc[t], 0, 0, 0);
                    acc[t] = __builtin_amdgcn_mfma_f32_16x16x32_bf16(ah, bl, acc[t], 0, 0, 0);
                    acc[t] = __builtin_amdgcn_mfma_f32_16x16x32_bf16(al, bh, acc[t], 0, 0, 0);
                }
            }
        }
        int row0 = wv * 16 + (lane >> 4) * 4;
        #pragma unroll
        for (int t = 0; t < 4; t++)
            #pragma unroll
            for (int v = 0; v < 4; v++)
                Gh[(size_t)c * 4096 + (row0 + v) * 64 + t * 16 + fm] = f2bf(acc[t][v]);
        return;
    }

    int q = bid - BB;
    int Msz = wave_sum64(img_lens, lane);
    int Mt = (Msz + 127) >> 7, Nt = (Nsz + 127) >> 7;
    if (q >= Mt * Nt) return;                 // dead tile: block-uniform early exit
    int m0 = (q / Nt) * 128, n0 = (q % Nt) * 128;

    int rw = (wv & 1) * 64;
    int cw = (wv >> 1) * 64;
    int srow = lane >> 2;
    // GLL dst is lane-ordered; XOR swizzle applied on the GLOBAL k-group
    int scol = ((lane & 3) ^ ((srow >> 1) & 3)) * 8;
    int fkS = ((lane >> 4) ^ ((fm >> 1) & 3)) * 8;

    f32x4 acc[4][4] = {};

    auto STAGE = [&](int buf, int kc) {
        int k0 = kc * 32;
        #pragma unroll
        for (int j = 0; j < 2; j++) {
            int seg = wv * 2 + j;
            int row = seg * 16 + srow;
            int rA = m0 + row; if (rA > Msz - 1) rA = Msz - 1;   // edge clamp
            int rB = n0 + row; if (rB > Nsz - 1) rB = Nsz - 1;   // (junk T unread)
            size_t ga = (size_t)rA * GK + k0 + scol;
            size_t gb = (size_t)rB * GK + k0 + scol;
            GLL(Ah + ga, &lds[buf][0][seg * 512]);
            GLL(Al + ga, &lds[buf][1][seg * 512]);
            GLL(Bh + gb, &lds[buf][2][seg * 512]);
            GLL(Bl + gb, &lds[buf][3][seg * 512]);
        }
    };
    auto COMPUTE = [&](int buf) {
        bf16x8 fah[4], fal[4], fbh[4], fbl[4];
        #pragma unroll
        for (int t = 0; t < 4; t++) {
            int offa = (rw + t * 16 + fm) * 32 + fkS;
            int offb = (cw + t * 16 + fm) * 32 + fkS;
            fah[t] = *(const bf16x8*)&lds[buf][0][offa];
            fal[t] = *(const bf16x8*)&lds[buf][1][offa];
            fbh[t] = *(const bf16x8*)&lds[buf][2][offb];
            fbl[t] = *(const bf16x8*)&lds[buf][3][offb];
        }
        #pragma unroll
        for (int mt = 0; mt < 4; mt++)
            #pragma unroll
            for (int nt = 0; nt < 4; nt++) {
                acc[mt][nt] = __builtin_amdgcn_mfma_f32_16x16x32_bf16(
                    fah[mt], fbh[nt], acc[mt][nt], 0, 0, 0);
                acc[mt][nt] = __builtin_amdgcn_mfma_f32_16x16x32_bf16(
                    fah[mt], fbl[nt], acc[mt][nt], 0, 0, 0);
                acc[mt][nt] = __builtin_amdgcn_mfma_f32_16x16x32_bf16(
                    fal[mt], fbh[nt], acc[mt][nt], 0, 0, 0);
            }
    };

    // Counted-vmcnt barrier: each wave waits for ITS stage-k loads (the 8
    // newest — stage k+1 — stay in flight), THEN barriers; after the barrier
    // every wave's stage-k data is in LDS. asm memory clobbers on both sides
    // keep all memory ops from crossing the raw barrier.
    #define KSTEP_WAIT(N) do { \
        asm volatile("s_waitcnt vmcnt(" #N ")" ::: "memory"); \
        __builtin_amdgcn_s_barrier(); \
        asm volatile("" ::: "memory"); \
    } while (0)

    STAGE(0, 0);
    STAGE(1, 1);
    for (int u = 0; u < 10; ++u) {           // computes steps 3u, 3u+1, 3u+2
        KSTEP_WAIT(8);
        STAGE(2, 3 * u + 2);
        COMPUTE(0);
        KSTEP_WAIT(8);
        STAGE(0, 3 * u + 3);
        COMPUTE(1);
        KSTEP_WAIT(8);
        STAGE(1, 3 * u + 4);
        COMPUTE(2);
    }
    KSTEP_WAIT(8);                            // step 30 (buf 0): stage31 in flight
    COMPUTE(0);
    KSTEP_WAIT(0);                            // step 31 (buf 1): drain last stage
    COMPUTE(1);
    #undef KSTEP_WAIT

    int orow0 = m0 + rw + (lane >> 4) * 4;
    int ocol0 = n0 + cw + fm;
    #pragma unroll
    for (int mt = 0; mt < 4; mt++)
        #pragma unroll
        for (int nt = 0; nt < 4; nt++)
            #pragma unroll
            for (int v = 0; v < 4; v++)
                T[(size_t)(orow0 + mt * 16 + v) * GN + ocol0 + nt * 16] = acc[mt][nt][v];
}

// Epilogue: one block per (c, image-group-of-4). Fixed costs (Gh load+swizzle,
// fragment extraction, prefix scans, per-c constants) amortized 4x; per-image
// pipeline identical to the proven single-image version (numerics unchanged).
#define MST 72   // sM row stride in ushorts (144 B, 16B-aligned)
__global__ __launch_bounds__(256) void epi_kernel(
        const float* __restrict__ T, const unsigned short* __restrict__ Gh,
        const int* __restrict__ img_lens, const int* __restrict__ cap_lens,
        const float* __restrict__ alpha,
        const float* __restrict__ invI, const float* __restrict__ invC,
        float* __restrict__ out) {
    int c = blockIdx.x, ig = blockIdx.y;
    __shared__ __align__(16) unsigned short sGh[64 * 64];
    __shared__ __align__(16) unsigned short sMh[48 * MST];
    __shared__ __align__(16) float Hsh[36][68];
    __shared__ float numSh[36];
    __shared__ float part[36][4];

    int tid = threadIdx.x;
    int lane = tid & 63, wv = tid >> 6;
    int fm = lane & 15, fk8 = (lane >> 4) * 8;
    int hf = lane >> 5, l5 = lane & 31;

    // one inclusive scan of img_lens; per-image exclusive prefix via shfl
    int vI = img_lens[lane], incI = vI;
    #pragma unroll
    for (int off = 1; off < 64; off <<= 1) {
        int t = __shfl_up(incI, off, 64);
        if (lane >= off) incI += t;
    }
    int pC = wave_excl_at(cap_lens, c, lane);
    int lc = cap_lens[c];

    {   // swizzled store: row r slot kg -> LDS slot kg ^ (r&7)
        const uint4* gh = (const uint4*)(Gh + (size_t)c * 4096);
        int rowg = tid >> 3, kg = tid & 7;
        int d = (rowg << 3) | (kg ^ (rowg & 7));
        ((uint4*)sGh)[d] = gh[tid];
        ((uint4*)sGh)[d + 256] = gh[tid + 256];
    }
    for (int t = tid; t < 12 * MST; t += 256) sMh[36 * MST + t] = 0;
    __syncthreads();

    bf16x8 gfh[2];
    #pragma unroll
    for (int ks = 0; ks < 2; ks++) {
        int kg8 = ks * 4 + (lane >> 4);
        int off = (wv * 16 + fm) * 64 + (kg8 ^ (fm & 7)) * 8;
        gfh[ks] = *(const bf16x8*)&sGh[off];
    }

    float a_mix = 1.0f / (1.0f + __expf(-alpha[0]));
    float oma = 1.0f - a_mix;
    float invC0 = invC[c * WW + l5];
    float invC1 = (l5 + 32 < WW) ? invC[c * WW + l5 + 32] : 0.f;
    bool v0 = l5 < lc, v1 = (l5 + 32) < lc;

    for (int ii = 0; ii < 4; ++ii) {
        int i = ig * 4 + ii;
        int li = __shfl(vI, i, 64);
        int pI = __shfl(incI - vI, i, 64);

        for (int r = wv * 2 + hf; r < li; r += 8) {
            float inv_ir = invI[i * RR + r];
            const float* Trow = T + (size_t)(pI + r) * GN + pC;
            float T0 = v0 ? Trow[l5] : 0.f;      // guard: beyond-N' memory may be junk
            float T1 = v1 ? Trow[l5 + 32] : 0.f;
            float S0 = v0 ? (T0 * inv_ir * invC0) : -2.f;
            float S1 = v1 ? (T1 * inv_ir * invC1) : -2.f;
            float mv; int mi;
            if (S1 > S0) { mv = S1; mi = l5 + 32; } else { mv = S0; mi = l5; }
            #pragma unroll
            for (int m = 1; m < 32; m <<= 1) {
                float ov = __shfl_xor(mv, m, 32);
                int oi = __shfl_xor(mi, m, 32);
                if (ov > mv || (ov == mv && oi < mi)) { mv = ov; mi = oi; }
            }
            float e0 = v0 ? __expf((S0 - mv) * 10.f) : 0.f;
            float e1 = v1 ? __expf((S1 - mv) * 10.f) : 0.f;
            float ss = e0 + e1, nm = fmaf(e0, T0, e1 * T1);
            #pragma unroll
            for (int m = 1; m < 32; m <<= 1) {
                ss += __shfl_xor(ss, m, 32);
                nm += __shfl_xor(nm, m, 32);
            }
            float Tmi = (mi < 32) ? __shfl(T0, mi, 32) : __shfl(T1, mi - 32, 32);
            float scale = a_mix / ss;
            float m0 = e0 * scale + (l5 == mi ? oma : 0.f);
            float m1 = e1 * scale + (l5 + 32 == mi ? oma : 0.f);
            if (l5 == 0) numSh[r] = fmaf(nm, scale, oma * Tmi);
            sMh[r * MST + l5] = f2bf(m0);
            sMh[r * MST + l5 + 32] = f2bf(m1);
        }
        __syncthreads();

        // stale sMh rows in [li, 36) from a previous image only feed output
        // rows >= li, which are overwritten with -1 (MFMA row r depends only
        // on A-row r) — safe.
        int quad4 = (lane >> 4) * 4;
        #pragma unroll
        for (int mt = 0; mt < 3; mt++) {
            f32x4 acc = {0.f, 0.f, 0.f, 0.f};
            #pragma unroll
            for (int ks = 0; ks < 2; ks++) {
                int off = (mt * 16 + fm) * MST + ks * 32 + fk8;
                bf16x8 mh = *(const bf16x8*)&sMh[off];
                acc = __builtin_amdgcn_mfma_f32_16x16x32_bf16(mh, gfh[ks], acc, 0, 0, 0);
            }
            #pragma unroll
            for (int v = 0; v < 4; v++) {
                int row = mt * 16 + quad4 + v;
                if (row < RR) Hsh[row][wv * 16 + fm] = acc[v];
            }
        }
        __syncthreads();

        if (tid < 144) {
            int r = tid >> 2, j = tid & 3;
            const bf16x8* mh = (const bf16x8*)&sMh[r * MST + j * 16];
            float p = 0.f;
            #pragma unroll
            for (int g = 0; g < 2; g++) {
                bf16x8 h8 = mh[g];
                #pragma unroll
                for (int qq = 0; qq < 8; qq++) {
                    float m = bf2f((unsigned short)h8[qq]);
                    p = fmaf(m, Hsh[r][j * 16 + g * 8 + qq], p);
                }
            }
            part[r][j] = p;
        }
        __syncthreads();
        if (tid < RR) {
            float den2 = part[tid][0] + part[tid][1] + part[tid][2] + part[tid][3];
            float res = (tid < li) ? (numSh[tid] / (sqrtf(den2) + EPSF)) : -1.0f;
            out[((size_t)i * BB + c) * RR + tid] = res;
        }
        __syncthreads();   // WAR: numSh/part/sMh reused by next image
    }
}

extern "C" void kernel_launch(void* const* d_in, const int* in_sizes, int n_in,
                              void* d_out, int out_size, void* d_ws, size_t ws_size,
                              hipStream_t stream) {
    const float* imgs = (const float*)d_in[0];
    const float* caps = (const float*)d_in[1];
    const int* img_lens = (const int*)d_in[2];
    const int* cap_lens = (const int*)d_in[3];
    const float* alpha = (const float*)d_in[4];
    float* out = (float*)d_out;

    float* ws = (float*)d_ws;
    float* invI = ws;                              // 2304
    float* invC = ws + BB * RR;                    // 3200
    float* T = invC + BB * WW;                     // 7372800 (worst case)
    unsigned short* Ah = (unsigned short*)(T + (size_t)GM * GN);
    unsigned short* Al = Ah + (size_t)GM * GK;
    unsigned short* Bh = Al + (size_t)GM * GK;
    unsigned short* Bl = Bh + (size_t)GN * GK;
    unsigned short* Gbh = Bl + (size_t)GN * GK;    // 64*4096 bf16

    phase1_kernel<<<(GM + GN) / 4, 256, 0, stream>>>(
        imgs, caps, img_lens, cap_lens, Ah, Al, Bh, Bl, invI, invC);
    phase2_kernel<<<BB + 450, 256, 0, stream>>>(
        Ah, Al, Bh, Bl, img_lens, cap_lens, Gbh, T);
    epi_kernel<<<dim3(BB, BB / 4), 256, 0, stream>>>(
        T, Gbh, img_lens, cap_lens, alpha, invI, invC, out);
}

// Round 7
// 127.687 us; speedup vs baseline: 1.0259x; 1.0199x over previous
//
#include <hip/hip_runtime.h>
#include <math.h>

#define BB 64
#define RR 36
#define WW 50
#define DD 1024
#define EPSF 1e-8f

#define GM 2304   // 64*36
#define GN 3200   // 64*50
#define GK 1024

typedef __attribute__((ext_vector_type(8))) short bf16x8;
typedef __attribute__((ext_vector_type(4))) float f32x4;

#define GLL(src, dst) __builtin_amdgcn_global_load_lds( \
    (const __attribute__((address_space(1))) void*)(src), \
    (__attribute__((address_space(3))) void*)(dst), 16, 0, 0)

__device__ __forceinline__ unsigned short f2bf(float x) {
    unsigned int u = __float_as_uint(x);
    unsigned int r = (u + 0x7fffu + ((u >> 16) & 1u)) >> 16;   // RTN-even
    return (unsigned short)r;
}
__device__ __forceinline__ float bf2f(unsigned short h) {
    return __uint_as_float(((unsigned int)h) << 16);
}

// Redundant per-wave 64-wide scans over the 64-entry lens arrays (cheap; avoids
// an extra kernel + cross-block dependency for prefix sums).
__device__ __forceinline__ int wave_sum64(const int* __restrict__ a, int lane) {
    int v = a[lane];
    #pragma unroll
    for (int off = 32; off > 0; off >>= 1) v += __shfl_xor(v, off, 64);
    return v;
}
__device__ __forceinline__ int wave_excl_at(const int* __restrict__ a, int idx, int lane) {
    int v = a[lane], inc = v;
    #pragma unroll
    for (int off = 1; off < 64; off <<= 1) {
        int t = __shfl_up(inc, off, 64);
        if (lane >= off) inc += t;
    }
    return __shfl(inc - v, idx, 64);
}

// Phase 1: wave-per-row hi/lo split + row norm, writing VALID rows only, packed
// (validity compaction: ~51% of rows are valid on average). No barriers.
__global__ __launch_bounds__(256) void phase1_kernel(
        const float* __restrict__ imgs, const float* __restrict__ caps,
        const int* __restrict__ img_lens, const int* __restrict__ cap_lens,
        unsigned short* __restrict__ Ah, unsigned short* __restrict__ Al,
        unsigned short* __restrict__ Bh, unsigned short* __restrict__ Bl,
        float* __restrict__ invI, float* __restrict__ invC) {
    int tid = threadIdx.x;
    int lane = tid & 63, wv = tid >> 6;
    int row = blockIdx.x * 4 + wv;          // GM divisible by 4: no straddle
    const float* X;
    unsigned short *H, *L;
    float* invN;
    size_t srcr;
    int dst;
    if (row < GM) {
        int i = row / RR, r = row - i * RR;
        if (r >= img_lens[i]) return;        // wave-uniform exit; no barriers
        dst = wave_excl_at(img_lens, i, lane) + r;
        X = imgs; H = Ah; L = Al; invN = invI; srcr = (size_t)row;
    } else {
        int rc = row - GM;
        int c = rc / WW, w = rc - c * WW;
        if (w >= cap_lens[c]) return;
        dst = wave_excl_at(cap_lens, c, lane) + w;
        X = caps; H = Bh; L = Bl; invN = invC; srcr = (size_t)rc;
    }
    const float4* src = (const float4*)(X + srcr * DD);
    ushort4* Hd = (ushort4*)H + (size_t)dst * 256;
    ushort4* Ld = (ushort4*)L + (size_t)dst * 256;
    float ss = 0.f;
    #pragma unroll
    for (int j = 0; j < 4; j++) {
        float4 v = src[j * 64 + lane];
        float f[4] = {v.x, v.y, v.z, v.w};
        ushort4 hh, ll;
        unsigned short* hp = (unsigned short*)&hh;
        unsigned short* lp = (unsigned short*)&ll;
        #pragma unroll
        for (int jj = 0; jj < 4; jj++) {
            unsigned short hb = f2bf(f[jj]);
            hp[jj] = hb;
            lp[jj] = f2bf(f[jj] - bf2f(hb));
            ss = fmaf(f[jj], f[jj], ss);
        }
        Hd[j * 64 + lane] = hh;
        Ld[j * 64 + lane] = ll;
    }
    #pragma unroll
    for (int off = 32; off > 0; off >>= 1) ss += __shfl_down(ss, off, 64);
    if (lane == 0) invN[srcr] = 1.0f / (sqrtf(ss) + EPSF);   // original (i,r)/(c,w) index
}

// Phase 2: blocks [0,64) = gram (compacted B rows at prefC[c]); blocks
// [64, 64+450) = 128x128 GEMM over the COMPACTED M'xN'xK problem.
// BK=64: 16 k-steps (vs 32) halves the number of per-step stage-drain stalls.
// 2 x 64 KiB buffers = 128 KiB LDS — free, since ~130 live tiles < 256 CUs
// means occupancy is grid-capped at 1 block/CU regardless of LDS use.
__global__ __launch_bounds__(256) void phase2_kernel(
        const unsigned short* __restrict__ Ah, const unsigned short* __restrict__ Al,
        const unsigned short* __restrict__ Bh, const unsigned short* __restrict__ Bl,
        const int* __restrict__ img_lens, const int* __restrict__ cap_lens,
        unsigned short* __restrict__ Gh, float* __restrict__ T) {
    int bid = blockIdx.x, tid = threadIdx.x;
    int lane = tid & 63, wv = tid >> 6;
    int fm = lane & 15;
    __shared__ __align__(16) unsigned short lds[2][4][8192];   // 128 KiB

    int Nsz = wave_sum64(cap_lens, lane);

    if (bid < BB) {
        // ---- gram: G[c] = caps_c . caps_c^T (hi/lo 3-MFMA), K-chunks of 128.
        int c = bid;
        int pc = wave_excl_at(cap_lens, c, lane);
        unsigned short* H16 = &lds[0][0][0];   // 64 rows x 128 u (16 KiB)
        unsigned short* L16 = &lds[0][1][0];
        f32x4 acc[4] = {};
        for (int k0 = 0; k0 < GK; k0 += 128) {
            __syncthreads();                   // prev-iter reads done
            #pragma unroll
            for (int j = 0; j < 4; j++) {
                int R = (wv * 4 + j) * 4 + (lane >> 4);
                int rowR = pc + R;
                if (rowR > Nsz - 1) rowR = Nsz - 1;   // garbage killed in epi (m=0)
                int gg = (lane & 15) ^ (R & 7);       // XOR swizzle, 16B granules
                size_t srcoff = (size_t)rowR * GK + k0 + gg * 8;
                GLL(Bh + srcoff, &H16[(wv * 4 + j) * 512]);
                GLL(Bl + srcoff, &L16[(wv * 4 + j) * 512]);
            }
            __syncthreads();                   // drains vmcnt(0)
            #pragma unroll
            for (int ks = 0; ks < 4; ks++) {
                int Ra = wv * 16 + fm;
                int qa = ks * 4 + (lane >> 4);
                int oa = Ra * 128 + (qa ^ (Ra & 7)) * 8;
                bf16x8 ah = *(const bf16x8*)&H16[oa];
                bf16x8 al = *(const bf16x8*)&L16[oa];
                #pragma unroll
                for (int t = 0; t < 4; t++) {
                    int Rb = t * 16 + fm;
                    int ob = Rb * 128 + (qa ^ (Rb & 7)) * 8;
                    bf16x8 bh = *(const bf16x8*)&H16[ob];
                    bf16x8 bl = *(const bf16x8*)&L16[ob];
                    acc[t] = __builtin_amdgcn_mfma_f32_16x16x32_bf16(ah, bh, acc[t], 0, 0, 0);
                    acc[t] = __builtin_amdgcn_mfma_f32_16x16x32_bf16(ah, bl, acc[t], 0, 0, 0);
                    acc[t] = __builtin_amdgcn_mfma_f32_16x16x32_bf16(al, bh, acc[t], 0, 0, 0);
                }
            }
        }
        int row0 = wv * 16 + (lane >> 4) * 4;
        #pragma unroll
        for (int t = 0; t < 4; t++)
            #pragma unroll
            for (int v = 0; v < 4; v++)
                Gh[(size_t)c * 4096 + (row0 + v) * 64 + t * 16 + fm] = f2bf(acc[t][v]);
        return;
    }

    int q = bid - BB;
    int Msz = wave_sum64(img_lens, lane);
    int Mt = (Msz + 127) >> 7, Nt = (Nsz + 127) >> 7;
    if (q >= Mt * Nt) return;                 // dead tile: block-uniform early exit
    int m0 = (q / Nt) * 128, n0 = (q % Nt) * 128;

    int rw = (wv & 1) * 64;
    int cw = (wv >> 1) * 64;
    int quad = lane >> 4;
    int srow8 = lane >> 3;                    // staging: 8 rows per GLL seg
    // GLL dst is lane-ordered (linear); inverse XOR swizzle on the GLOBAL
    // k-group: LDS slot (lane&7) holds global k-group (lane&7)^(row&7).
    int scol = ((lane & 7) ^ (srow8 & 7)) * 8;
    f32x4 acc[4][4] = {};

    auto STAGE = [&](int buf, int kc) {
        int k0 = kc * 64;
        #pragma unroll
        for (int j = 0; j < 4; j++) {
            int seg = wv * 4 + j;             // 16 segs x 8 rows = 128 rows
            int row = seg * 8 + srow8;
            int rA = m0 + row; if (rA > Msz - 1) rA = Msz - 1;   // edge clamp
            int rB = n0 + row; if (rB > Nsz - 1) rB = Nsz - 1;   // (junk T unread)
            size_t ga = (size_t)rA * GK + k0 + scol;
            size_t gb = (size_t)rB * GK + k0 + scol;
            GLL(Ah + ga, &lds[buf][0][seg * 512]);
            GLL(Al + ga, &lds[buf][1][seg * 512]);
            GLL(Bh + gb, &lds[buf][2][seg * 512]);
            GLL(Bl + gb, &lds[buf][3][seg * 512]);
        }
    };
    auto COMPUTE = [&](int buf) {
        // kk ascending keeps MFMA accumulation order identical to BK=32 version
        #pragma unroll
        for (int kk = 0; kk < 2; kk++) {
            bf16x8 fah[4], fal[4], fbh[4], fbl[4];
            #pragma unroll
            for (int t = 0; t < 4; t++) {
                int Ra = rw + t * 16 + fm;
                int Rb = cw + t * 16 + fm;
                int qa = kk * 4 + quad;
                int offa = Ra * 64 + (qa ^ (Ra & 7)) * 8;
                int offb = Rb * 64 + (qa ^ (Rb & 7)) * 8;
                fah[t] = *(const bf16x8*)&lds[buf][0][offa];
                fal[t] = *(const bf16x8*)&lds[buf][1][offa];
                fbh[t] = *(const bf16x8*)&lds[buf][2][offb];
                fbl[t] = *(const bf16x8*)&lds[buf][3][offb];
            }
            #pragma unroll
            for (int mt = 0; mt < 4; mt++)
                #pragma unroll
                for (int nt = 0; nt < 4; nt++) {
                    acc[mt][nt] = __builtin_amdgcn_mfma_f32_16x16x32_bf16(
                        fah[mt], fbh[nt], acc[mt][nt], 0, 0, 0);
                    acc[mt][nt] = __builtin_amdgcn_mfma_f32_16x16x32_bf16(
                        fah[mt], fbl[nt], acc[mt][nt], 0, 0, 0);
                    acc[mt][nt] = __builtin_amdgcn_mfma_f32_16x16x32_bf16(
                        fal[mt], fbh[nt], acc[mt][nt], 0, 0, 0);
                }
        }
    };

    // 2-phase pipeline: stage(k+1) issued before compute(k); single barrier
    // per k-step drains vmcnt(0) (next buffer ready) + orders LDS WAR.
    STAGE(0, 0);
    __syncthreads();
    int cur = 0;
    for (int kc = 1; kc < 16; ++kc) {
        STAGE(cur ^ 1, kc);
        COMPUTE(cur);
        __syncthreads();
        cur ^= 1;
    }
    COMPUTE(cur);

    int orow0 = m0 + rw + (lane >> 4) * 4;
    int ocol0 = n0 + cw + fm;
    #pragma unroll
    for (int mt = 0; mt < 4; mt++)
        #pragma unroll
        for (int nt = 0; nt < 4; nt++)
            #pragma unroll
            for (int v = 0; v < 4; v++)
                T[(size_t)(orow0 + mt * 16 + v) * GN + ocol0 + nt * 16] = acc[mt][nt][v];
}

// Epilogue: one block per (c, i); T indexed via compaction prefixes; row loop
// bounded by li (skips invalid image regions entirely). Round-4 proven form.
#define MST 72   // sM row stride in ushorts (144 B, 16B-aligned)
__global__ __launch_bounds__(256) void epi_kernel(
        const float* __restrict__ T, const unsigned short* __restrict__ Gh,
        const int* __restrict__ img_lens, const int* __restrict__ cap_lens,
        const float* __restrict__ alpha,
        const float* __restrict__ invI, const float* __restrict__ invC,
        float* __restrict__ out) {
    int c = blockIdx.x, i = blockIdx.y;
    __shared__ __align__(16) unsigned short sGh[64 * 64];
    __shared__ __align__(16) unsigned short sMh[48 * MST];
    __shared__ __align__(16) float Hsh[36][68];
    __shared__ float numSh[36];
    __shared__ float part[36][4];

    int tid = threadIdx.x;
    int lane = tid & 63, wv = tid >> 6;
    int fm = lane & 15, fk8 = (lane >> 4) * 8;
    int hf = lane >> 5, l5 = lane & 31;

    int pI = wave_excl_at(img_lens, i, lane);
    int pC = wave_excl_at(cap_lens, c, lane);
    int lc = cap_lens[c], li = img_lens[i];

    {   // swizzled store: row r slot kg -> LDS slot kg ^ (r&7)
        const uint4* gh = (const uint4*)(Gh + (size_t)c * 4096);
        int rowg = tid >> 3, kg = tid & 7;
        int d = (rowg << 3) | (kg ^ (rowg & 7));
        ((uint4*)sGh)[d] = gh[tid];
        ((uint4*)sGh)[d + 256] = gh[tid + 256];
    }
    for (int t = tid; t < 12 * MST; t += 256) sMh[36 * MST + t] = 0;
    __syncthreads();

    bf16x8 gfh[2];
    #pragma unroll
    for (int ks = 0; ks < 2; ks++) {
        int kg8 = ks * 4 + (lane >> 4);
        int off = (wv * 16 + fm) * 64 + (kg8 ^ (fm & 7)) * 8;
        gfh[ks] = *(const bf16x8*)&sGh[off];
    }

    float a_mix = 1.0f / (1.0f + __expf(-alpha[0]));
    float oma = 1.0f - a_mix;
    float invC0 = invC[c * WW + l5];
    float invC1 = (l5 + 32 < WW) ? invC[c * WW + l5 + 32] : 0.f;
    bool v0 = l5 < lc, v1 = (l5 + 32) < lc;

    for (int r = wv * 2 + hf; r < li; r += 8) {
        float inv_ir = invI[i * RR + r];
        const float* Trow = T + (size_t)(pI + r) * GN + pC;
        float T0 = v0 ? Trow[l5] : 0.f;          // guard: beyond-N' memory may be junk
        float T1 = v1 ? Trow[l5 + 32] : 0.f;
        float S0 = v0 ? (T0 * inv_ir * invC0) : -2.f;
        float S1 = v1 ? (T1 * inv_ir * invC1) : -2.f;
        float mv; int mi;
        if (S1 > S0) { mv = S1; mi = l5 + 32; } else { mv = S0; mi = l5; }
        #pragma unroll
        for (int m = 1; m < 32; m <<= 1) {
            float ov = __shfl_xor(mv, m, 32);
            int oi = __shfl_xor(mi, m, 32);
            if (ov > mv || (ov == mv && oi < mi)) { mv = ov; mi = oi; }
        }
        float e0 = v0 ? __expf((S0 - mv) * 10.f) : 0.f;
        float e1 = v1 ? __expf((S1 - mv) * 10.f) : 0.f;
        float ss = e0 + e1, nm = fmaf(e0, T0, e1 * T1);
        #pragma unroll
        for (int m = 1; m < 32; m <<= 1) {
            ss += __shfl_xor(ss, m, 32);
            nm += __shfl_xor(nm, m, 32);
        }
        float Tmi = (mi < 32) ? __shfl(T0, mi, 32) : __shfl(T1, mi - 32, 32);
        float scale = a_mix / ss;
        float m0 = e0 * scale + (l5 == mi ? oma : 0.f);
        float m1 = e1 * scale + (l5 + 32 == mi ? oma : 0.f);
        if (l5 == 0) numSh[r] = fmaf(nm, scale, oma * Tmi);
        sMh[r * MST + l5] = f2bf(m0);
        sMh[r * MST + l5 + 32] = f2bf(m1);
    }
    __syncthreads();

    int quad4 = (lane >> 4) * 4;
    #pragma unroll
    for (int mt = 0; mt < 3; mt++) {
        f32x4 acc = {0.f, 0.f, 0.f, 0.f};
        #pragma unroll
        for (int ks = 0; ks < 2; ks++) {
            int off = (mt * 16 + fm) * MST + ks * 32 + fk8;
            bf16x8 mh = *(const bf16x8*)&sMh[off];
            acc = __builtin_amdgcn_mfma_f32_16x16x32_bf16(mh, gfh[ks], acc, 0, 0, 0);
        }
        #pragma unroll
        for (int v = 0; v < 4; v++) {
            int row = mt * 16 + quad4 + v;
            if (row < RR) Hsh[row][wv * 16 + fm] = acc[v];
        }
    }
    __syncthreads();

    if (tid < 144) {
        int r = tid >> 2, j = tid & 3;
        const bf16x8* mh = (const bf16x8*)&sMh[r * MST + j * 16];
        float p = 0.f;
        #pragma unroll
        for (int g = 0; g < 2; g++) {
            bf16x8 h8 = mh[g];
            #pragma unroll
            for (int qq = 0; qq < 8; qq++) {
                float m = bf2f((unsigned short)h8[qq]);
                p = fmaf(m, Hsh[r][j * 16 + g * 8 + qq], p);
            }
        }
        part[r][j] = p;
    }
    __syncthreads();
    if (tid < RR) {
        float den2 = part[tid][0] + part[tid][1] + part[tid][2] + part[tid][3];
        float res = (tid < li) ? (numSh[tid] / (sqrtf(den2) + EPSF)) : -1.0f;
        out[((size_t)i * BB + c) * RR + tid] = res;
    }
}

extern "C" void kernel_launch(void* const* d_in, const int* in_sizes, int n_in,
                              void* d_out, int out_size, void* d_ws, size_t ws_size,
                              hipStream_t stream) {
    const float* imgs = (const float*)d_in[0];
    const float* caps = (const float*)d_in[1];
    const int* img_lens = (const int*)d_in[2];
    const int* cap_lens = (const int*)d_in[3];
    const float* alpha = (const float*)d_in[4];
    float* out = (float*)d_out;

    float* ws = (float*)d_ws;
    float* invI = ws;                              // 2304
    float* invC = ws + BB * RR;                    // 3200
    float* T = invC + BB * WW;                     // 7372800 (worst case)
    unsigned short* Ah = (unsigned short*)(T + (size_t)GM * GN);
    unsigned short* Al = Ah + (size_t)GM * GK;
    unsigned short* Bh = Al + (size_t)GM * GK;
    unsigned short* Bl = Bh + (size_t)GN * GK;
    unsigned short* Gbh = Bl + (size_t)GN * GK;    // 64*4096 bf16

    phase1_kernel<<<(GM + GN) / 4, 256, 0, stream>>>(
        imgs, caps, img_lens, cap_lens, Ah, Al, Bh, Bl, invI, invC);
    phase2_kernel<<<BB + 450, 256, 0, stream>>>(
        Ah, Al, Bh, Bl, img_lens, cap_lens, Gbh, T);
    epi_kernel<<<dim3(BB, BB), 256, 0, stream>>>(
        T, Gbh, img_lens, cap_lens, alpha, invI, invC, out);
}

// Round 8
// 125.679 us; speedup vs baseline: 1.0423x; 1.0160x over previous
//
#include <hip/hip_runtime.h>
#include <math.h>

#define BB 64
#define RR 36
#define WW 50
#define DD 1024
#define EPSF 1e-8f

#define GM 2304   // 64*36
#define GN 3200   // 64*50
#define GK 1024

typedef __attribute__((ext_vector_type(8))) short bf16x8;
typedef __attribute__((ext_vector_type(4))) float f32x4;

#define GLL(src, dst) __builtin_amdgcn_global_load_lds( \
    (const __attribute__((address_space(1))) void*)(src), \
    (__attribute__((address_space(3))) void*)(dst), 16, 0, 0)

__device__ __forceinline__ unsigned short f2bf(float x) {
    unsigned int u = __float_as_uint(x);
    unsigned int r = (u + 0x7fffu + ((u >> 16) & 1u)) >> 16;   // RTN-even
    return (unsigned short)r;
}
__device__ __forceinline__ float bf2f(unsigned short h) {
    return __uint_as_float(((unsigned int)h) << 16);
}

// Redundant per-wave 64-wide scans over the 64-entry lens arrays (cheap; avoids
// an extra kernel + cross-block dependency for prefix sums).
__device__ __forceinline__ int wave_sum64(const int* __restrict__ a, int lane) {
    int v = a[lane];
    #pragma unroll
    for (int off = 32; off > 0; off >>= 1) v += __shfl_xor(v, off, 64);
    return v;
}
__device__ __forceinline__ int wave_excl_at(const int* __restrict__ a, int idx, int lane) {
    int v = a[lane], inc = v;
    #pragma unroll
    for (int off = 1; off < 64; off <<= 1) {
        int t = __shfl_up(inc, off, 64);
        if (lane >= off) inc += t;
    }
    return __shfl(inc - v, idx, 64);
}

// Phase 1: wave-per-row hi/lo split + row norm, writing VALID rows only, packed
// (validity compaction: ~51% of rows are valid on average). No barriers.
__global__ __launch_bounds__(256) void phase1_kernel(
        const float* __restrict__ imgs, const float* __restrict__ caps,
        const int* __restrict__ img_lens, const int* __restrict__ cap_lens,
        unsigned short* __restrict__ Ah, unsigned short* __restrict__ Al,
        unsigned short* __restrict__ Bh, unsigned short* __restrict__ Bl,
        float* __restrict__ invI, float* __restrict__ invC) {
    int tid = threadIdx.x;
    int lane = tid & 63, wv = tid >> 6;
    int row = blockIdx.x * 4 + wv;          // GM divisible by 4: no straddle
    const float* X;
    unsigned short *H, *L;
    float* invN;
    size_t srcr;
    int dst;
    if (row < GM) {
        int i = row / RR, r = row - i * RR;
        if (r >= img_lens[i]) return;        // wave-uniform exit; no barriers
        dst = wave_excl_at(img_lens, i, lane) + r;
        X = imgs; H = Ah; L = Al; invN = invI; srcr = (size_t)row;
    } else {
        int rc = row - GM;
        int c = rc / WW, w = rc - c * WW;
        if (w >= cap_lens[c]) return;
        dst = wave_excl_at(cap_lens, c, lane) + w;
        X = caps; H = Bh; L = Bl; invN = invC; srcr = (size_t)rc;
    }
    const float4* src = (const float4*)(X + srcr * DD);
    ushort4* Hd = (ushort4*)H + (size_t)dst * 256;
    ushort4* Ld = (ushort4*)L + (size_t)dst * 256;
    float ss = 0.f;
    #pragma unroll
    for (int j = 0; j < 4; j++) {
        float4 v = src[j * 64 + lane];
        float f[4] = {v.x, v.y, v.z, v.w};
        ushort4 hh, ll;
        unsigned short* hp = (unsigned short*)&hh;
        unsigned short* lp = (unsigned short*)&ll;
        #pragma unroll
        for (int jj = 0; jj < 4; jj++) {
            unsigned short hb = f2bf(f[jj]);
            hp[jj] = hb;
            lp[jj] = f2bf(f[jj] - bf2f(hb));
            ss = fmaf(f[jj], f[jj], ss);
        }
        Hd[j * 64 + lane] = hh;
        Ld[j * 64 + lane] = ll;
    }
    #pragma unroll
    for (int off = 32; off > 0; off >>= 1) ss += __shfl_down(ss, off, 64);
    if (lane == 0) invN[srcr] = 1.0f / (sqrtf(ss) + EPSF);   // original (i,r)/(c,w) index
}

// Phase 2: blocks [0,64) = gram (compacted B rows at prefC[c]); blocks
// [64, 64+450) = 128x128 GEMM over the COMPACTED M'xN'xK problem, depth-2
// prefetch (3 LDS buffers, counted vmcnt(8), raw s_barrier). Best-measured
// configuration (r4, 126.1 us).
__global__ __launch_bounds__(256) void phase2_kernel(
        const unsigned short* __restrict__ Ah, const unsigned short* __restrict__ Al,
        const unsigned short* __restrict__ Bh, const unsigned short* __restrict__ Bl,
        const int* __restrict__ img_lens, const int* __restrict__ cap_lens,
        unsigned short* __restrict__ Gh, float* __restrict__ T) {
    int bid = blockIdx.x, tid = threadIdx.x;
    int lane = tid & 63, wv = tid >> 6;
    int fm = lane & 15;
    __shared__ __align__(16) unsigned short lds[3][4][4096];   // 96 KiB

    int Nsz = wave_sum64(cap_lens, lane);

    if (bid < BB) {
        // ---- gram: G[c] = caps_c . caps_c^T (hi/lo 3-MFMA), K-chunks of 128.
        int c = bid;
        int pc = wave_excl_at(cap_lens, c, lane);
        unsigned short* H16 = &lds[0][0][0];   // 64 rows x 128 u (16 KiB)
        unsigned short* L16 = &lds[0][2][0];
        f32x4 acc[4] = {};
        for (int k0 = 0; k0 < GK; k0 += 128) {
            __syncthreads();                   // prev-iter reads done
            #pragma unroll
            for (int j = 0; j < 4; j++) {
                int R = (wv * 4 + j) * 4 + (lane >> 4);
                int rowR = pc + R;
                if (rowR > Nsz - 1) rowR = Nsz - 1;   // garbage killed in epi (m=0)
                int gg = (lane & 15) ^ (R & 7);       // XOR swizzle, 16B granules
                size_t srcoff = (size_t)rowR * GK + k0 + gg * 8;
                GLL(Bh + srcoff, &H16[(wv * 4 + j) * 512]);
                GLL(Bl + srcoff, &L16[(wv * 4 + j) * 512]);
            }
            __syncthreads();                   // drains vmcnt(0)
            #pragma unroll
            for (int ks = 0; ks < 4; ks++) {
                int Ra = wv * 16 + fm;
                int qa = ks * 4 + (lane >> 4);
                int oa = Ra * 128 + (qa ^ (Ra & 7)) * 8;
                bf16x8 ah = *(const bf16x8*)&H16[oa];
                bf16x8 al = *(const bf16x8*)&L16[oa];
                #pragma unroll
                for (int t = 0; t < 4; t++) {
                    int Rb = t * 16 + fm;
                    int ob = Rb * 128 + (qa ^ (Rb & 7)) * 8;
                    bf16x8 bh = *(const bf16x8*)&H16[ob];
                    bf16x8 bl = *(const bf16x8*)&L16[ob];
                    acc[t] = __builtin_amdgcn_mfma_f32_16x16x32_bf16(ah, bh, acc[t], 0, 0, 0);
                    acc[t] = __builtin_amdgcn_mfma_f32_16x16x32_bf16(ah, bl, acc[t], 0, 0, 0);
                    acc[t] = __builtin_amdgcn_mfma_f32_16x16x32_bf16(al, bh, acc[t], 0, 0, 0);
                }
            }
        }
        int row0 = wv * 16 + (lane >> 4) * 4;
        #pragma unroll
        for (int t = 0; t < 4; t++)
            #pragma unroll
            for (int v = 0; v < 4; v++)
                Gh[(size_t)c * 4096 + (row0 + v) * 64 + t * 16 + fm] = f2bf(acc[t][v]);
        return;
    }

    int q = bid - BB;
    int Msz = wave_sum64(img_lens, lane);
    int Mt = (Msz + 127) >> 7, Nt = (Nsz + 127) >> 7;
    if (q >= Mt * Nt) return;                 // dead tile: block-uniform early exit
    int m0 = (q / Nt) * 128, n0 = (q % Nt) * 128;

    int rw = (wv & 1) * 64;
    int cw = (wv >> 1) * 64;
    int srow = lane >> 2;
    // GLL dst is lane-ordered; XOR swizzle applied on the GLOBAL k-group
    int scol = ((lane & 3) ^ ((srow >> 1) & 3)) * 8;
    int fkS = ((lane >> 4) ^ ((fm >> 1) & 3)) * 8;

    f32x4 acc[4][4] = {};

    auto STAGE = [&](int buf, int kc) {
        int k0 = kc * 32;
        #pragma unroll
        for (int j = 0; j < 2; j++) {
            int seg = wv * 2 + j;
            int row = seg * 16 + srow;
            int rA = m0 + row; if (rA > Msz - 1) rA = Msz - 1;   // edge clamp
            int rB = n0 + row; if (rB > Nsz - 1) rB = Nsz - 1;   // (junk T unread)
            size_t ga = (size_t)rA * GK + k0 + scol;
            size_t gb = (size_t)rB * GK + k0 + scol;
            GLL(Ah + ga, &lds[buf][0][seg * 512]);
            GLL(Al + ga, &lds[buf][1][seg * 512]);
            GLL(Bh + gb, &lds[buf][2][seg * 512]);
            GLL(Bl + gb, &lds[buf][3][seg * 512]);
        }
    };
    auto COMPUTE = [&](int buf) {
        bf16x8 fah[4], fal[4], fbh[4], fbl[4];
        #pragma unroll
        for (int t = 0; t < 4; t++) {
            int offa = (rw + t * 16 + fm) * 32 + fkS;
            int offb = (cw + t * 16 + fm) * 32 + fkS;
            fah[t] = *(const bf16x8*)&lds[buf][0][offa];
            fal[t] = *(const bf16x8*)&lds[buf][1][offa];
            fbh[t] = *(const bf16x8*)&lds[buf][2][offb];
            fbl[t] = *(const bf16x8*)&lds[buf][3][offb];
        }
        #pragma unroll
        for (int mt = 0; mt < 4; mt++)
            #pragma unroll
            for (int nt = 0; nt < 4; nt++) {
                acc[mt][nt] = __builtin_amdgcn_mfma_f32_16x16x32_bf16(
                    fah[mt], fbh[nt], acc[mt][nt], 0, 0, 0);
                acc[mt][nt] = __builtin_amdgcn_mfma_f32_16x16x32_bf16(
                    fah[mt], fbl[nt], acc[mt][nt], 0, 0, 0);
                acc[mt][nt] = __builtin_amdgcn_mfma_f32_16x16x32_bf16(
                    fal[mt], fbh[nt], acc[mt][nt], 0, 0, 0);
            }
    };

    // Counted-vmcnt barrier: each wave waits for ITS stage-k loads (the 8
    // newest — stage k+1 — stay in flight), THEN barriers; after the barrier
    // every wave's stage-k data is in LDS. asm memory clobbers on both sides
    // keep all memory ops from crossing the raw barrier.
    #define KSTEP_WAIT(N) do { \
        asm volatile("s_waitcnt vmcnt(" #N ")" ::: "memory"); \
        __builtin_amdgcn_s_barrier(); \
        asm volatile("" ::: "memory"); \
    } while (0)

    STAGE(0, 0);
    STAGE(1, 1);
    for (int u = 0; u < 10; ++u) {           // computes steps 3u, 3u+1, 3u+2
        KSTEP_WAIT(8);
        STAGE(2, 3 * u + 2);
        COMPUTE(0);
        KSTEP_WAIT(8);
        STAGE(0, 3 * u + 3);
        COMPUTE(1);
        KSTEP_WAIT(8);
        STAGE(1, 3 * u + 4);
        COMPUTE(2);
    }
    KSTEP_WAIT(8);                            // step 30 (buf 0): stage31 in flight
    COMPUTE(0);
    KSTEP_WAIT(0);                            // step 31 (buf 1): drain last stage
    COMPUTE(1);
    #undef KSTEP_WAIT

    int orow0 = m0 + rw + (lane >> 4) * 4;
    int ocol0 = n0 + cw + fm;
    #pragma unroll
    for (int mt = 0; mt < 4; mt++)
        #pragma unroll
        for (int nt = 0; nt < 4; nt++)
            #pragma unroll
            for (int v = 0; v < 4; v++)
                T[(size_t)(orow0 + mt * 16 + v) * GN + ocol0 + nt * 16] = acc[mt][nt][v];
}

// Epilogue: one block per (c, i); T indexed via compaction prefixes; row loop
// bounded by li (skips invalid image regions entirely).
#define MST 72   // sM row stride in ushorts (144 B, 16B-aligned)
__global__ __launch_bounds__(256) void epi_kernel(
        const float* __restrict__ T, const unsigned short* __restrict__ Gh,
        const int* __restrict__ img_lens, const int* __restrict__ cap_lens,
        const float* __restrict__ alpha,
        const float* __restrict__ invI, const float* __restrict__ invC,
        float* __restrict__ out) {
    int c = blockIdx.x, i = blockIdx.y;
    __shared__ __align__(16) unsigned short sGh[64 * 64];
    __shared__ __align__(16) unsigned short sMh[48 * MST];
    __shared__ __align__(16) float Hsh[36][68];
    __shared__ float numSh[36];
    __shared__ float part[36][4];

    int tid = threadIdx.x;
    int lane = tid & 63, wv = tid >> 6;
    int fm = lane & 15, fk8 = (lane >> 4) * 8;
    int hf = lane >> 5, l5 = lane & 31;

    int pI = wave_excl_at(img_lens, i, lane);
    int pC = wave_excl_at(cap_lens, c, lane);
    int lc = cap_lens[c], li = img_lens[i];

    {   // swizzled store: row r slot kg -> LDS slot kg ^ (r&7)
        const uint4* gh = (const uint4*)(Gh + (size_t)c * 4096);
        int rowg = tid >> 3, kg = tid & 7;
        int d = (rowg << 3) | (kg ^ (rowg & 7));
        ((uint4*)sGh)[d] = gh[tid];
        ((uint4*)sGh)[d + 256] = gh[tid + 256];
    }
    for (int t = tid; t < 12 * MST; t += 256) sMh[36 * MST + t] = 0;
    __syncthreads();

    bf16x8 gfh[2];
    #pragma unroll
    for (int ks = 0; ks < 2; ks++) {
        int kg8 = ks * 4 + (lane >> 4);
        int off = (wv * 16 + fm) * 64 + (kg8 ^ (fm & 7)) * 8;
        gfh[ks] = *(const bf16x8*)&sGh[off];
    }

    float a_mix = 1.0f / (1.0f + __expf(-alpha[0]));
    float oma = 1.0f - a_mix;
    float invC0 = invC[c * WW + l5];
    float invC1 = (l5 + 32 < WW) ? invC[c * WW + l5 + 32] : 0.f;
    bool v0 = l5 < lc, v1 = (l5 + 32) < lc;

    for (int r = wv * 2 + hf; r < li; r += 8) {
        float inv_ir = invI[i * RR + r];
        const float* Trow = T + (size_t)(pI + r) * GN + pC;
        float T0 = v0 ? Trow[l5] : 0.f;          // guard: beyond-N' memory may be junk
        float T1 = v1 ? Trow[l5 + 32] : 0.f;
        float S0 = v0 ? (T0 * inv_ir * invC0) : -2.f;
        float S1 = v1 ? (T1 * inv_ir * invC1) : -2.f;
        float mv; int mi;
        if (S1 > S0) { mv = S1; mi = l5 + 32; } else { mv = S0; mi = l5; }
        #pragma unroll
        for (int m = 1; m < 32; m <<= 1) {
            float ov = __shfl_xor(mv, m, 32);
            int oi = __shfl_xor(mi, m, 32);
            if (ov > mv || (ov == mv && oi < mi)) { mv = ov; mi = oi; }
        }
        float e0 = v0 ? __expf((S0 - mv) * 10.f) : 0.f;
        float e1 = v1 ? __expf((S1 - mv) * 10.f) : 0.f;
        float ss = e0 + e1, nm = fmaf(e0, T0, e1 * T1);
        #pragma unroll
        for (int m = 1; m < 32; m <<= 1) {
            ss += __shfl_xor(ss, m, 32);
            nm += __shfl_xor(nm, m, 32);
        }
        float Tmi = (mi < 32) ? __shfl(T0, mi, 32) : __shfl(T1, mi - 32, 32);
        float scale = a_mix / ss;
        float m0 = e0 * scale + (l5 == mi ? oma : 0.f);
        float m1 = e1 * scale + (l5 + 32 == mi ? oma : 0.f);
        if (l5 == 0) numSh[r] = fmaf(nm, scale, oma * Tmi);
        sMh[r * MST + l5] = f2bf(m0);
        sMh[r * MST + l5 + 32] = f2bf(m1);
    }
    __syncthreads();

    int quad4 = (lane >> 4) * 4;
    #pragma unroll
    for (int mt = 0; mt < 3; mt++) {
        f32x4 acc = {0.f, 0.f, 0.f, 0.f};
        #pragma unroll
        for (int ks = 0; ks < 2; ks++) {
            int off = (mt * 16 + fm) * MST + ks * 32 + fk8;
            bf16x8 mh = *(const bf16x8*)&sMh[off];
            acc = __builtin_amdgcn_mfma_f32_16x16x32_bf16(mh, gfh[ks], acc, 0, 0, 0);
        }
        #pragma unroll
        for (int v = 0; v < 4; v++) {
            int row = mt * 16 + quad4 + v;
            if (row < RR) Hsh[row][wv * 16 + fm] = acc[v];
        }
    }
    __syncthreads();

    if (tid < 144) {
        int r = tid >> 2, j = tid & 3;
        const bf16x8* mh = (const bf16x8*)&sMh[r * MST + j * 16];
        float p = 0.f;
        #pragma unroll
        for (int g = 0; g < 2; g++) {
            bf16x8 h8 = mh[g];
            #pragma unroll
            for (int qq = 0; qq < 8; qq++) {
                float m = bf2f((unsigned short)h8[qq]);
                p = fmaf(m, Hsh[r][j * 16 + g * 8 + qq], p);
            }
        }
        part[r][j] = p;
    }
    __syncthreads();
    if (tid < RR) {
        float den2 = part[tid][0] + part[tid][1] + part[tid][2] + part[tid][3];
        float res = (tid < li) ? (numSh[tid] / (sqrtf(den2) + EPSF)) : -1.0f;
        out[((size_t)i * BB + c) * RR + tid] = res;
    }
}

extern "C" void kernel_launch(void* const* d_in, const int* in_sizes, int n_in,
                              void* d_out, int out_size, void* d_ws, size_t ws_size,
                              hipStream_t stream) {
    const float* imgs = (const float*)d_in[0];
    const float* caps = (const float*)d_in[1];
    const int* img_lens = (const int*)d_in[2];
    const int* cap_lens = (const int*)d_in[3];
    const float* alpha = (const float*)d_in[4];
    float* out = (float*)d_out;

    float* ws = (float*)d_ws;
    float* invI = ws;                              // 2304
    float* invC = ws + BB * RR;                    // 3200
    float* T = invC + BB * WW;                     // 7372800 (worst case)
    unsigned short* Ah = (unsigned short*)(T + (size_t)GM * GN);
    unsigned short* Al = Ah + (size_t)GM * GK;
    unsigned short* Bh = Al + (size_t)GM * GK;
    unsigned short* Bl = Bh + (size_t)GN * GK;
    unsigned short* Gbh = Bl + (size_t)GN * GK;    // 64*4096 bf16

    phase1_kernel<<<(GM + GN) / 4, 256, 0, stream>>>(
        imgs, caps, img_lens, cap_lens, Ah, Al, Bh, Bl, invI, invC);
    phase2_kernel<<<BB + 450, 256, 0, stream>>>(
        Ah, Al, Bh, Bl, img_lens, cap_lens, Gbh, T);
    epi_kernel<<<dim3(BB, BB), 256, 0, stream>>>(
        T, Gbh, img_lens, cap_lens, alpha, invI, invC, out);
}